// Round 9
// baseline (151.689 us; speedup 1.0000x reference)
//
#include <hip/hip_runtime.h>

#define T_LEN 2048
#define NSTATE 64
#define NCHUNK 16
#define CH_S 128      // stored steps per chunk
#define WARM 64       // warm-up steps (10.7*mu)
#define RK 16         // renorm every 16 steps (scale cancels in LLR)

// ---- DPP helpers (VALU pipe, no DS ops). ctrl must be a compile-time constant. ----
template <int CTRL>
__device__ __forceinline__ float dpp_add(float v) {
    int r = __builtin_amdgcn_update_dpp(0, __float_as_int(v), CTRL, 0xF, 0xF, true);
    return v + __int_as_float(r);
}
// Sum of all 64 lanes, valid in lane 63 (row_shr 1/2/4/8, row_bcast15, row_bcast31).
__device__ __forceinline__ float red63(float v) {
    v = dpp_add<0x111>(v);
    v = dpp_add<0x112>(v);
    v = dpp_add<0x114>(v);
    v = dpp_add<0x118>(v);
    v = dpp_add<0x142>(v);
    v = dpp_add<0x143>(v);
    return v;
}
__device__ __forceinline__ float bcast63(float v) {
    return __uint_as_float(__builtin_amdgcn_readlane(__float_as_uint(v), 63));
}
// v + v[lane^1] via quad_perm [1,0,3,2]
__device__ __forceinline__ float pair_sum_xor1(float v) {
    return dpp_add<0xB1>(v);
}
// cheap fp32 -> bf16 (round-half-up)
__device__ __forceinline__ unsigned short bf16_of(float f) {
    return (unsigned short)((__float_as_uint(f) + 0x8000u) >> 16);
}
__device__ __forceinline__ float bf16_lo(unsigned u) { return __uint_as_float(u << 16); }
__device__ __forceinline__ float bf16_hi(unsigned u) { return __uint_as_float(u & 0xffff0000u); }

// GEN_POLY = ('1111001','1011011'), mu=6, NS=64. State s: shift reg, newest bit = MSB.
// o0 parity mask 57, o1 mask 27. log2-domain branch metric:
// x_s = kE*la + (kE*c0)*l0 + (kE*c1)*l1, kE = 0.5*log2(e); gamma(s,0)=2^x_s, gamma(s,1)=2^-x_s.

// ---------------- Kernel 1: beta-only chunked sweep ----------------
// wave = (b, chunk): warm-up then CH_S stored steps; wsB[b][t][s] = bf16 beta_{t+1}[s].
__global__ __launch_bounds__(256, 4)
void bcjr_beta_kernel(const float* __restrict__ llr_ch,   // [B][2*T]
                      const float* __restrict__ llr_a,    // [B][T]
                      unsigned short* __restrict__ wsB)   // [B][T][64]
{
    const int wave  = blockIdx.x * 4 + (threadIdx.x >> 6);
    const int lane  = threadIdx.x & 63;
    const int chunk = wave & (NCHUNK - 1);
    const int b     = wave >> 4;

    const float c0 = 1.0f - 2.0f * (float)(__popc(lane & 57) & 1);
    const float c1 = 1.0f - 2.0f * (float)(__popc(lane & 27) & 1);
    const float kE = 0.5f * 1.442695040888963f;
    const float k0 = kE * c0, k1 = kE * c1;

    const float* chp = llr_ch + (size_t)b * (2 * T_LEN);
    const float* lap = llr_a  + (size_t)b * T_LEN;
    unsigned short* w = wsB + (size_t)b * T_LEN * NSTATE;

    const int bs0 = lane >> 1;
    const int bs1 = 32 + (lane >> 1);
    const int t0 = chunk * CH_S;
    const int te = (chunk == NCHUNK - 1) ? (t0 + CH_S) : (t0 + CH_S + WARM);
    float state = 1.0f / 64.0f;   // exact beta_T at sequence end; warm init otherwise

    for (int g = te - RK; g >= t0; g -= RK) {
        const bool store = (g < t0 + CH_S);
        #pragma unroll
        for (int h = 1; h >= 0; --h) {
            const int gb = g + 8 * h;
            const float4* c4 = (const float4*)(chp + 2 * gb);
            const float4* a4 = (const float4*)(lap + gb);
            float4 cc[4], aa[2];
            #pragma unroll
            for (int i = 0; i < 4; ++i) cc[i] = c4[i];
            #pragma unroll
            for (int i = 0; i < 2; ++i) aa[i] = a4[i];
            unsigned short* wb = w + (size_t)gb * NSTATE + lane;
            #pragma unroll
            for (int i = 7; i >= 0; --i) {
                float l0 = (i & 1) ? cc[i >> 1].z : cc[i >> 1].x;
                float l1 = (i & 1) ? cc[i >> 1].w : cc[i >> 1].y;
                float la = ((const float*)aa)[i];
                if (store) wb[i * NSTATE] = bf16_of(state);   // beta_{t+1}
                float x   = fmaf(la, kE, fmaf(l0, k0, l1 * k1));
                float g0v = exp2f(x);
                float g1v = __builtin_amdgcn_rcpf(g0v);
                float t0v = __shfl(state, bs0, 64);
                float t1v = __shfl(state, bs1, 64);
                state = fmaf(g0v, t0v, g1v * t1v);
            }
        }
        float s = bcast63(red63(state));
        state = state * __builtin_amdgcn_rcpf(s);
    }
}

// ---------------- Kernel 2: alpha sweep with fused LLR emission ----------------
// wave = (b, chunk): alpha warm-up, then 128 fused steps. At step t, alpha_t and
// gamma_t live in registers; beta_{t+1} row (128 B) is loaded coalesced from wsB
// (addresses independent of the recursion -> prefetched per 8-step half-group).
// llr_t = log(sum_s a_t[s] g0[s] B[s>>1]) - log(sum_s a_t[s] g1[s] B[32|(s>>1)]).
__global__ __launch_bounds__(256, 4)
void bcjr_alpha_llr_kernel(const float* __restrict__ llr_ch,
                           const float* __restrict__ llr_a,
                           const unsigned short* __restrict__ wsB,
                           float* __restrict__ out)
{
    const int wave  = blockIdx.x * 4 + (threadIdx.x >> 6);
    const int lane  = threadIdx.x & 63;
    const int chunk = wave & (NCHUNK - 1);
    const int b     = wave >> 4;

    const float c0 = 1.0f - 2.0f * (float)(__popc(lane & 57) & 1);
    const float c1 = 1.0f - 2.0f * (float)(__popc(lane & 27) & 1);
    const float kE = 0.5f * 1.442695040888963f;
    const float k0 = kE * c0, k1 = kE * c1;
    const float LN2 = 0.69314718055994531f;

    const float* chp = llr_ch + (size_t)b * (2 * T_LEN);
    const float* lap = llr_a  + (size_t)b * T_LEN;
    float* outp      = out    + (size_t)b * T_LEN;

    const int  fs0 = 2 * (lane & 31);
    const bool fhi = (lane >= 32);
    const int t0 = chunk * CH_S;
    const int ts = (chunk == 0) ? t0 : t0 - WARM;
    float state = (chunk == 0) ? ((lane == 0) ? 1.0f : 0.0f) : (1.0f / 64.0f);

    // ---- warm-up: light alpha steps ----
    for (int g = ts; g < t0; g += RK) {
        #pragma unroll
        for (int h = 0; h < 2; ++h) {
            const int gb = g + 8 * h;
            const float4* c4 = (const float4*)(chp + 2 * gb);
            const float4* a4 = (const float4*)(lap + gb);
            float4 cc[4], aa[2];
            #pragma unroll
            for (int i = 0; i < 4; ++i) cc[i] = c4[i];
            #pragma unroll
            for (int i = 0; i < 2; ++i) aa[i] = a4[i];
            #pragma unroll
            for (int i = 0; i < 8; ++i) {
                float l0 = (i & 1) ? cc[i >> 1].z : cc[i >> 1].x;
                float l1 = (i & 1) ? cc[i >> 1].w : cc[i >> 1].y;
                float la = ((const float*)aa)[i];
                float x   = fmaf(la, kE, fmaf(l0, k0, l1 * k1));
                float g0v = exp2f(x);
                float g1v = __builtin_amdgcn_rcpf(g0v);
                float s0  = pair_sum_xor1(state * g0v);
                float s1  = pair_sum_xor1(state * g1v);
                float a0  = __shfl(s0, fs0, 64);
                float a1  = __shfl(s1, fs0, 64);
                state = fhi ? a1 : a0;
            }
        }
        float s = bcast63(red63(state));
        state = state * __builtin_amdgcn_rcpf(s);
    }

    // ---- fused: alpha step + LLR emission ----
    // beta row t (64 ushorts = 32 dwords): lane needs elem l>>1 (dword l>>2,
    // half (l&2)) and elem 32+(l>>1) (dword 16+(l>>2)).
    const unsigned* brow = (const unsigned*)(wsB + (size_t)b * T_LEN * NSTATE);
    const int  di0 = lane >> 2;
    const int  di1 = 16 + (lane >> 2);
    const bool dhi = (lane & 2) != 0;
    float keep = 0.0f;

    for (int g = t0; g < t0 + CH_S; g += RK) {
        #pragma unroll
        for (int h = 0; h < 2; ++h) {
            const int gb = g + 8 * h;
            const float4* c4 = (const float4*)(chp + 2 * gb);
            const float4* a4 = (const float4*)(lap + gb);
            float4 cc[4], aa[2];
            #pragma unroll
            for (int i = 0; i < 4; ++i) cc[i] = c4[i];
            #pragma unroll
            for (int i = 0; i < 2; ++i) aa[i] = a4[i];
            // prefetch beta dwords for the 8 steps (independent of recursion)
            unsigned bu0[8], bu1[8];
            const unsigned* r = brow + (size_t)gb * 32;
            #pragma unroll
            for (int i = 0; i < 8; ++i) { bu0[i] = r[i * 32 + di0]; bu1[i] = r[i * 32 + di1]; }
            #pragma unroll
            for (int i = 0; i < 8; ++i) {
                const int t = gb + i;
                float l0 = (i & 1) ? cc[i >> 1].z : cc[i >> 1].x;
                float l1 = (i & 1) ? cc[i >> 1].w : cc[i >> 1].y;
                float la = ((const float*)aa)[i];
                float x   = fmaf(la, kE, fmaf(l0, k0, l1 * k1));
                float g0v = exp2f(x);
                float g1v = __builtin_amdgcn_rcpf(g0v);
                float b0v = dhi ? bf16_hi(bu0[i]) : bf16_lo(bu0[i]);   // beta[s>>1]
                float b1v = dhi ? bf16_hi(bu1[i]) : bf16_lo(bu1[i]);   // beta[32|(s>>1)]
                float ag0 = state * g0v;
                float ag1 = state * g1v;
                float n0 = red63(ag0 * b0v);
                float n1 = red63(ag1 * b1v);
                float llr = LN2 * (__log2f(n0) - __log2f(n1));         // valid in lane 63
                float lb  = bcast63(llr);
                keep = (lane == (t & 63)) ? lb : keep;
                // alpha update (reuses ag0/ag1)
                float s0 = pair_sum_xor1(ag0);
                float s1 = pair_sum_xor1(ag1);
                float a0 = __shfl(s0, fs0, 64);
                float a1 = __shfl(s1, fs0, 64);
                state = fhi ? a1 : a0;
            }
        }
        if ((g & 63) == 48) outp[g - 48 + lane] = keep;   // 64 llrs, coalesced
        float s = bcast63(red63(state));
        state = state * __builtin_amdgcn_rcpf(s);
    }
}

extern "C" void kernel_launch(void* const* d_in, const int* in_sizes, int n_in,
                              void* d_out, int out_size, void* d_ws, size_t ws_size,
                              hipStream_t stream) {
    const float* llr_ch = (const float*)d_in[0];
    const float* llr_a  = (const float*)d_in[1];
    float* out = (float*)d_out;
    unsigned short* wsB = (unsigned short*)d_ws;

    int B = in_sizes[0] / (2 * T_LEN);   // 256
    int n_waves = B * NCHUNK;            // 4096 waves per kernel
    hipLaunchKernelGGL(bcjr_beta_kernel, dim3(n_waves / 4), dim3(256), 0, stream,
                       llr_ch, llr_a, wsB);
    hipLaunchKernelGGL(bcjr_alpha_llr_kernel, dim3(n_waves / 4), dim3(256), 0, stream,
                       llr_ch, llr_a, wsB, out);
}

// Round 10
// 142.212 us; speedup vs baseline: 1.0666x; 1.0666x over previous
//
#include <hip/hip_runtime.h>

#define T_LEN 2048
#define NSTATE 64
// K2 (alpha/LLR) chunking
#define NCHUNK 16
#define CH_S 128
#define WARM 64
// K1 (beta) chunking — smaller chunks for 8 waves/SIMD occupancy
#define NCH_B 32
#define CH_B 64
#define RK 16         // renorm every 16 steps (scale cancels in LLR)

// ---- DPP helpers (VALU pipe). ctrl must be a compile-time constant. ----
template <int CTRL>
__device__ __forceinline__ float dpp_add(float v) {
    int r = __builtin_amdgcn_update_dpp(0, __float_as_int(v), CTRL, 0xF, 0xF, true);
    return v + __int_as_float(r);
}
// Sum of all 64 lanes, valid in lane 63.
__device__ __forceinline__ float red63(float v) {
    v = dpp_add<0x111>(v);   // row_shr 1
    v = dpp_add<0x112>(v);   // row_shr 2
    v = dpp_add<0x114>(v);   // row_shr 4
    v = dpp_add<0x118>(v);   // row_shr 8
    v = dpp_add<0x142>(v);   // row_bcast15
    v = dpp_add<0x143>(v);   // row_bcast31
    return v;
}
// Half sums: lane31 = sum(lanes 0..31), lane63 = sum(lanes 32..63).
__device__ __forceinline__ float red_half(float v) {
    v = dpp_add<0x111>(v);
    v = dpp_add<0x112>(v);
    v = dpp_add<0x114>(v);
    v = dpp_add<0x118>(v);
    v = dpp_add<0x142>(v);   // row_bcast15: lane31 += rows0; lane63 += row2
    return v;
}
__device__ __forceinline__ float rdlane(float v, int l) {
    return __uint_as_float(__builtin_amdgcn_readlane(__float_as_uint(v), l));
}
__device__ __forceinline__ float bcast63(float v) { return rdlane(v, 63); }
__device__ __forceinline__ float pair_sum_xor1(float v) { return dpp_add<0xB1>(v); }
__device__ __forceinline__ unsigned short bf16_of(float f) {
    return (unsigned short)((__float_as_uint(f) + 0x8000u) >> 16);
}
__device__ __forceinline__ float bf16_lo(unsigned u) { return __uint_as_float(u << 16); }
__device__ __forceinline__ float bf16_hi(unsigned u) { return __uint_as_float(u & 0xffff0000u); }

// GEN_POLY = ('1111001','1011011'), mu=6, NS=64. State s: shift reg, newest bit = MSB.
// o0 parity mask 57, o1 mask 27. log2-domain branch metric:
// x_s = kE*la + (kE*c0)*l0 + (kE*c1)*l1, kE = 0.5*log2(e); gamma(s,0)=2^x_s, gamma(s,1)=2^-x_s.

// ---------------- Kernel 1: beta-only sweep, 32 chunks of 64 (8 waves/SIMD) ----------------
__global__ __launch_bounds__(256, 8)
void bcjr_beta_kernel(const float* __restrict__ llr_ch,   // [B][2*T]
                      const float* __restrict__ llr_a,    // [B][T]
                      unsigned short* __restrict__ wsB)   // [B][T][64] bf16 beta_{t+1}
{
    const int wave  = blockIdx.x * 4 + (threadIdx.x >> 6);
    const int lane  = threadIdx.x & 63;
    const int chunk = wave & (NCH_B - 1);
    const int b     = wave >> 5;          // log2(NCH_B)=5

    const float c0 = 1.0f - 2.0f * (float)(__popc(lane & 57) & 1);
    const float c1 = 1.0f - 2.0f * (float)(__popc(lane & 27) & 1);
    const float kE = 0.5f * 1.442695040888963f;
    const float k0 = kE * c0, k1 = kE * c1;

    const float* chp = llr_ch + (size_t)b * (2 * T_LEN);
    const float* lap = llr_a  + (size_t)b * T_LEN;
    unsigned short* w = wsB + (size_t)b * T_LEN * NSTATE;

    const int bs0 = lane >> 1;
    const int bs1 = 32 + (lane >> 1);
    const int t0 = chunk * CH_B;
    const int te = (chunk == NCH_B - 1) ? (t0 + CH_B) : (t0 + CH_B + WARM);
    float state = 1.0f / 64.0f;   // exact beta_T at sequence end; warm init otherwise

    for (int g = te - RK; g >= t0; g -= RK) {
        const bool store = (g < t0 + CH_B);
        #pragma unroll
        for (int h = 1; h >= 0; --h) {
            const int gb = g + 8 * h;
            const float4* c4 = (const float4*)(chp + 2 * gb);
            const float4* a4 = (const float4*)(lap + gb);
            float4 cc[4], aa[2];
            #pragma unroll
            for (int i = 0; i < 4; ++i) cc[i] = c4[i];
            #pragma unroll
            for (int i = 0; i < 2; ++i) aa[i] = a4[i];
            unsigned short* wb = w + (size_t)gb * NSTATE + lane;
            #pragma unroll
            for (int i = 7; i >= 0; --i) {
                float l0 = (i & 1) ? cc[i >> 1].z : cc[i >> 1].x;
                float l1 = (i & 1) ? cc[i >> 1].w : cc[i >> 1].y;
                float la = ((const float*)aa)[i];
                if (store) wb[i * NSTATE] = bf16_of(state);   // beta_{t+1}
                float x   = fmaf(la, kE, fmaf(l0, k0, l1 * k1));
                float g0v = exp2f(x);
                float g1v = __builtin_amdgcn_rcpf(g0v);
                float t0v = __shfl(state, bs0, 64);
                float t1v = __shfl(state, bs1, 64);
                state = fmaf(g0v, t0v, g1v * t1v);
            }
        }
        float s = bcast63(red63(state));
        state = state * __builtin_amdgcn_rcpf(s);
    }
}

// ---------------- Kernel 2: alpha sweep with fused LLR emission ----------------
// LLR via flow identity: an[j] (pre-norm alpha_{t+1}) collects b=0 flows for j<32
// and b=1 flows for j>=32, so
//   n0 = sum_{j<32} an[j]*beta_{t+1}[j],  n1 = sum_{j>=32} an[j]*beta_{t+1}[j]
// -> one mul + 5-DPP half-reduce + 2 readlanes per step; single beta[lane] stream.
__global__ __launch_bounds__(256, 4)
void bcjr_alpha_llr_kernel(const float* __restrict__ llr_ch,
                           const float* __restrict__ llr_a,
                           const unsigned short* __restrict__ wsB,
                           float* __restrict__ out)
{
    const int wave  = blockIdx.x * 4 + (threadIdx.x >> 6);
    const int lane  = threadIdx.x & 63;
    const int chunk = wave & (NCHUNK - 1);
    const int b     = wave >> 4;

    const float c0 = 1.0f - 2.0f * (float)(__popc(lane & 57) & 1);
    const float c1 = 1.0f - 2.0f * (float)(__popc(lane & 27) & 1);
    const float kE = 0.5f * 1.442695040888963f;
    const float k0 = kE * c0, k1 = kE * c1;
    const float LN2 = 0.69314718055994531f;

    const float* chp = llr_ch + (size_t)b * (2 * T_LEN);
    const float* lap = llr_a  + (size_t)b * T_LEN;
    float* outp      = out    + (size_t)b * T_LEN;

    const int  fs0 = 2 * (lane & 31);
    const bool fhi = (lane >= 32);
    const int t0 = chunk * CH_S;
    const int ts = (chunk == 0) ? t0 : t0 - WARM;
    float state = (chunk == 0) ? ((lane == 0) ? 1.0f : 0.0f) : (1.0f / 64.0f);

    // ---- warm-up: light alpha steps ----
    for (int g = ts; g < t0; g += RK) {
        #pragma unroll
        for (int h = 0; h < 2; ++h) {
            const int gb = g + 8 * h;
            const float4* c4 = (const float4*)(chp + 2 * gb);
            const float4* a4 = (const float4*)(lap + gb);
            float4 cc[4], aa[2];
            #pragma unroll
            for (int i = 0; i < 4; ++i) cc[i] = c4[i];
            #pragma unroll
            for (int i = 0; i < 2; ++i) aa[i] = a4[i];
            #pragma unroll
            for (int i = 0; i < 8; ++i) {
                float l0 = (i & 1) ? cc[i >> 1].z : cc[i >> 1].x;
                float l1 = (i & 1) ? cc[i >> 1].w : cc[i >> 1].y;
                float la = ((const float*)aa)[i];
                float x   = fmaf(la, kE, fmaf(l0, k0, l1 * k1));
                float g0v = exp2f(x);
                float g1v = __builtin_amdgcn_rcpf(g0v);
                float s0  = pair_sum_xor1(state * g0v);
                float s1  = pair_sum_xor1(state * g1v);
                float a0  = __shfl(s0, fs0, 64);
                float a1  = __shfl(s1, fs0, 64);
                state = fhi ? a1 : a0;
            }
        }
        float s = bcast63(red63(state));
        state = state * __builtin_amdgcn_rcpf(s);
    }

    // ---- fused: alpha step + LLR emission ----
    const unsigned* brow = (const unsigned*)(wsB + (size_t)b * T_LEN * NSTATE);
    const int  bdw = lane >> 1;          // beta dword: element `lane` of each row
    const bool bhi = (lane & 1) != 0;
    float keep = 0.0f;

    for (int g = t0; g < t0 + CH_S; g += RK) {
        #pragma unroll
        for (int h = 0; h < 2; ++h) {
            const int gb = g + 8 * h;
            const float4* c4 = (const float4*)(chp + 2 * gb);
            const float4* a4 = (const float4*)(lap + gb);
            float4 cc[4], aa[2];
            #pragma unroll
            for (int i = 0; i < 4; ++i) cc[i] = c4[i];
            #pragma unroll
            for (int i = 0; i < 2; ++i) aa[i] = a4[i];
            // prefetch beta_{t+1}[lane] dwords for the 8 steps
            unsigned bu[8];
            const unsigned* r = brow + (size_t)gb * 32;
            #pragma unroll
            for (int i = 0; i < 8; ++i) bu[i] = r[i * 32 + bdw];
            #pragma unroll
            for (int i = 0; i < 8; ++i) {
                const int t = gb + i;
                float l0 = (i & 1) ? cc[i >> 1].z : cc[i >> 1].x;
                float l1 = (i & 1) ? cc[i >> 1].w : cc[i >> 1].y;
                float la = ((const float*)aa)[i];
                float x   = fmaf(la, kE, fmaf(l0, k0, l1 * k1));
                float g0v = exp2f(x);
                float g1v = __builtin_amdgcn_rcpf(g0v);
                float ag0 = state * g0v;
                float ag1 = state * g1v;
                float s0  = pair_sum_xor1(ag0);
                float s1  = pair_sum_xor1(ag1);
                float a0  = __shfl(s0, fs0, 64);
                float a1  = __shfl(s1, fs0, 64);
                float an  = fhi ? a1 : a0;          // alpha_{t+1}, pre-norm
                float bv  = bhi ? bf16_hi(bu[i]) : bf16_lo(bu[i]);   // beta_{t+1}[lane]
                float v   = red_half(an * bv);      // lane31 = n0, lane63 = n1
                float n0  = rdlane(v, 31);
                float n1  = rdlane(v, 63);
                float llr = LN2 * (__log2f(n0) - __log2f(n1));
                keep = (lane == (t & 63)) ? llr : keep;
                state = an;
            }
        }
        if ((g & 63) == 48) outp[g - 48 + lane] = keep;   // 64 llrs, coalesced
        float s = bcast63(red63(state));
        state = state * __builtin_amdgcn_rcpf(s);
    }
}

extern "C" void kernel_launch(void* const* d_in, const int* in_sizes, int n_in,
                              void* d_out, int out_size, void* d_ws, size_t ws_size,
                              hipStream_t stream) {
    const float* llr_ch = (const float*)d_in[0];
    const float* llr_a  = (const float*)d_in[1];
    float* out = (float*)d_out;
    unsigned short* wsB = (unsigned short*)d_ws;

    int B = in_sizes[0] / (2 * T_LEN);   // 256
    int nw_beta  = B * NCH_B;            // 8192 waves
    int nw_alpha = B * NCHUNK;           // 4096 waves
    hipLaunchKernelGGL(bcjr_beta_kernel, dim3(nw_beta / 4), dim3(256), 0, stream,
                       llr_ch, llr_a, wsB);
    hipLaunchKernelGGL(bcjr_alpha_llr_kernel, dim3(nw_alpha / 4), dim3(256), 0, stream,
                       llr_ch, llr_a, wsB, out);
}